// Round 9
// baseline (662.739 us; speedup 1.0000x reference)
//
#include <hip/hip_runtime.h>
#include <hip/hip_bf16.h>
#include <math.h>

#define NLAT_I 240
#define NLON_I 480
#define NLAT_O 361
#define NLON_O 720
#define CI_N 32
#define CO_N 32
#define K_N 7
#define WOFF 10
#define WLAT 21

#define PI_F 3.14159265358979323846f
#define TWOPI_F 6.28318530717958647692f
#define DLAT_V (PI_F / 360.0f)
#define DPHI_V (TWOPI_F / 720.0f)
#define CUTOFF_V (3.25f * PI_F / 120.0f)
#define DR_V (CUTOFF_V / 3.0f)
#define IDR_V (1.0f / DR_V)
#define DPH_V (TWOPI_F / 3.0f)
#define IDPH_V (1.0f / DPH_V)
#define QF_V (DLAT_V * DPHI_V)

#define PAD_T 64        // Toeplitz pad (covers fragment reach beyond support)
#define CT 64           // positions per work item
#define NBLK 512        // 64 blocks per partition x 8 partitions = 2 blocks/CU
#define NC45 45         // 720/16 column chunks
#define NE 7581         // 361*21

typedef __attribute__((ext_vector_type(8))) short short8v;
typedef __attribute__((ext_vector_type(16))) float f32x16;

__device__ __forceinline__ unsigned short f2bf(float f) {
  __hip_bfloat16 h = __float2bfloat16(f);   // RTNE
  union { __hip_bfloat16 b; unsigned short s; } u; u.b = h; return u.s;
}

// ---------------- psi evaluation --------------------------------------------
__device__ __forceinline__ void psi_eval(float ct, float st, float cg, float sg,
                                         float q, float bang, float v[7]) {
  float sb, cb;
  sincosf(bang, &sb, &cb);
  float dx = sg * cb - st;
  float dy = sg * sb;
  float dz = cg - ct;
  float c2 = dx * dx + dy * dy + dz * dz;
  float r = 2.0f * asinf(fminf(1.0f, 0.5f * sqrtf(c2)));
  if (r <= CUTOFF_V) {
    float xx = ct * cb * sg - st * cg;
    float yy = sb * sg;
    float phi = atan2f(yy, xx);
    if (phi < 0.0f) phi += TWOPI_F;
    v[0] = fmaxf(0.0f, 1.0f - r * IDR_V) * q;
#pragma unroll
    for (int k = 1; k < 7; ++k) {
      const float irdr = (float)(1 + (k - 1) / 3) * DR_V;
      const float ipph = (float)((k - 1) % 3) * DPH_V;
      float rad = fmaxf(0.0f, 1.0f - fabsf(r - irdr) * IDR_V);
      float dd = fabsf(phi - ipph);
      dd = fminf(dd, TWOPI_F - dd);
      float az = fmaxf(0.0f, 1.0f - dd * IDPH_V);
      v[k] = rad * az * q;
    }
  } else {
#pragma unroll
    for (int k = 0; k < 7; ++k) v[k] = 0.0f;
  }
}

// per-(t,d) lon window half-width: -1 empty, 360 full circle
__device__ __forceinline__ int windowB(int t, int d) {
  int tp = t + d - WOFF;
  if (tp < 0 || tp > NLAT_O - 1) return -1;
  float th = (float)t * DLAT_V, ga = (float)tp * DLAT_V;
  float st = sinf(th), ct = cosf(th), sg = sinf(ga), cg = cosf(ga);
  float den = st * sg;
  float num = cosf(CUTOFF_V) - ct * cg;
  if (den < 1e-9f) return (fabsf(th - ga) <= CUTOFF_V) ? 360 : -1;
  if (num >= den) return -1;
  if (num <= -den) return 360;
  int B = (int)ceilf(acosf(num / den) * (1.0f / DPHI_V)) + 1;  // +1 margin; psi masks
  return B > 360 ? 360 : B;
}

__device__ __forceinline__ int nsupOf(int B) { return (B >= 360) ? 720 : 2 * B + 1; }
__device__ __forceinline__ int widthOf(int B) {
  return (B < 0) ? 0 : ((nsupOf(B) + 129) & ~1);   // even
}

// ---------------- kernel 0: prep (w2, scans, wtab, bands, counters) ---------
__global__ void prep_kernel(const float* __restrict__ w, unsigned short* __restrict__ w2,
                            int* __restrict__ offsF, int* __restrict__ offsT,
                            int* __restrict__ wtab, float* __restrict__ sums,
                            int* __restrict__ itemPrefix, int* __restrict__ tband,
                            int* __restrict__ counters) {
  const int tid = threadIdx.x;
  __shared__ int temp[256];
  if (tid < 8) counters[tid] = 0;
  for (int idx = tid; idx < 361 * 7; idx += 256) sums[idx] = 0.0f;
  // w2[c16][o][kk] = bf16(w[o][i][k]) with ci=c16*16+kk, k=ci>>5, i=ci&31
  for (int idx = tid; idx < 14 * 32 * 16; idx += 256) {
    int kk = idx & 15; int o = (idx >> 4) & 31; int c16 = idx >> 9;
    int ci = c16 * 16 + kk; int i = ci & 31; int k = ci >> 5;
    w2[idx] = f2bf(w[(o * 32 + i) * 7 + k]);
  }
  for (int e = tid; e < NE; e += 256) {
    int t = e / 21, d = e % 21;
    int B = windowB(t, d);
    offsF[e] = (B >= 0) ? nsupOf(B) * 7 : 0;
    offsT[e] = 14 * widthOf(B);
  }
  for (int t = tid; t < 361; t += 256) {
    int Wt = 0;
    for (int d = 0; d < WLAT; ++d) {
      int B = windowB(t, d);
      if (B >= 0) Wt += ((31 + B) >> 4) + ((B + 15) >> 4) + 1;
    }
    wtab[t] = Wt;
  }
  __syncthreads();
  if (tid == 0) {
    // item prefix in natural t order, then 8 equal-work t-bands
    int run = 0;
    for (int t = 0; t < 361; ++t) {
      itemPrefix[t] = run;
      run += 6 * ((wtab[t] + CT - 1) / CT);
    }
    itemPrefix[361] = run;
    tband[0] = 0;
    for (int p = 1; p < 8; ++p) {
      long target = ((long)run * p) / 8;
      int T = tband[p - 1];
      while (T < 361 && itemPrefix[T] < target) ++T;
      tband[p] = T;
    }
    tband[8] = 361;
  }
  __syncthreads();
  // two-level exclusive scan for offsF then offsT (chunk = 30, 256*30 >= NE)
#pragma unroll 1
  for (int pass = 0; pass < 2; ++pass) {
    int* a = pass ? offsT : offsF;
    int s = tid * 30, e = s + 30; if (e > NE) e = NE; if (s > NE) s = NE;
    int sum = 0;
    for (int i = s; i < e; ++i) sum += a[i];
    temp[tid] = sum;
    __syncthreads();
    if (tid == 0) {
      int run = 0;
      for (int i = 0; i < 256; ++i) { int v = temp[i]; temp[i] = run; run += v; }
      a[NE] = run;
    }
    __syncthreads();
    int run = temp[tid];
    for (int i = s; i < e; ++i) { int v = a[i]; a[i] = run; run += v; }
    __syncthreads();
  }
}

// ---------------- kernel 1: bilinear upsample -> tiled bf16 XT --------------
// XT[t][c][i][kk] with b = c*16+kk  (wave A-load = contiguous 1KB)
__global__ void upsample_kernel(const float* __restrict__ x,
                                unsigned short* __restrict__ XT) {
  int idx = blockIdx.x * 256 + threadIdx.x;
  if (idx >= NLAT_O * NC45 * 512) return;
  int kk = idx & 15;
  int i = (idx >> 4) & 31;
  int c = (idx >> 9) % NC45;
  int t = idx / (NC45 * 512);
  int p = c * 16 + kk;

  double post = (double)t * (239.0 / 360.0);
  int i0 = (int)floor(post);
  if (i0 < 0) i0 = 0;
  if (i0 > NLAT_I - 1) i0 = NLAT_I - 1;
  int i1 = i0 + 1; if (i1 > NLAT_I - 1) i1 = NLAT_I - 1;
  float wt = (float)(post - (double)i0);

  double posp = (double)p * (2.0 / 3.0);
  double j0f = floor(posp);
  int j0 = ((int)j0f) % NLON_I;
  int j1 = (j0 + 1) % NLON_I;
  float wp = (float)(posp - j0f);

  const float* xi = x + (size_t)i * (NLAT_I * NLON_I);
  float a = xi[i0 * NLON_I + j0];
  float b = xi[i0 * NLON_I + j1];
  float cc = xi[i1 * NLON_I + j0];
  float d = xi[i1 * NLON_I + j1];
  float l0 = (1.0f - wt) * a + wt * cc;
  float l1 = (1.0f - wt) * b + wt * d;
  XT[idx] = f2bf((1.0f - wp) * l0 + wp * l1);
}

// ---------------- kernel 2: raw psi (f32) + fused per-(k,t) partial sums ----
__global__ void psi_raw_kernel(const int* __restrict__ offsF,
                               float* __restrict__ PSIF,
                               float* __restrict__ sums) {
  int t = blockIdx.x, d = blockIdx.y;
  int B = windowB(t, d);
  if (B < 0) return;
  int nsup = nsupOf(B);
  int bLo = (B >= 360) ? -360 : -B;
  int offF = offsF[t * 21 + d];
  int tp = t + d - WOFF;
  float th = (float)t * DLAT_V, ga = (float)tp * DLAT_V;
  float st, ct, sg, cg;
  sincosf(th, &st, &ct);
  sincosf(ga, &sg, &cg);
  float q = sg * QF_V;
  float acc[7];
#pragma unroll
  for (int k = 0; k < 7; ++k) acc[k] = 0.0f;
  for (int ix = threadIdx.x; ix < nsup; ix += 256) {
    float v[7];
    psi_eval(ct, st, cg, sg, q, (float)(bLo + ix) * DPHI_V, v);
#pragma unroll
    for (int k = 0; k < 7; ++k) { PSIF[offF + k * nsup + ix] = v[k]; acc[k] += v[k]; }
  }
#pragma unroll
  for (int k = 0; k < 7; ++k) {
    float a = acc[k];
    for (int off = 32; off > 0; off >>= 1) a += __shfl_down(a, off, 64);
    acc[k] = a;
  }
  __shared__ float red[4][7];
  int wid = threadIdx.x >> 6;
  if ((threadIdx.x & 63) == 0) {
#pragma unroll
    for (int k = 0; k < 7; ++k) red[wid][k] = acc[k];
  }
  __syncthreads();
  if (threadIdx.x == 0) {
#pragma unroll
    for (int k = 0; k < 7; ++k)
      atomicAdd(&sums[t * 7 + k], red[0][k] + red[1][k] + red[2][k] + red[3][k]);
  }
}

// ---------------- kernel 3: normalized bf16 Toeplitz (2 parity copies) ------
__global__ void psi_toep_kernel(const int* __restrict__ offsF,
                                const int* __restrict__ offsT,
                                const float* __restrict__ PSIF,
                                const float* __restrict__ sums,
                                unsigned short* __restrict__ PSIT) {
  int t = blockIdx.x, d = blockIdx.y;
  int B = windowB(t, d);
  if (B < 0) return;
  int nsup = nsupOf(B);
  int width = widthOf(B);
  int offF = offsF[t * 21 + d];
  int offT = offsT[t * 21 + d];
  float rc[7];
#pragma unroll
  for (int k = 0; k < 7; ++k) rc[k] = 1.0f / fmaxf(sums[t * 7 + k], 1e-8f);
  for (int ix = threadIdx.x; ix <= width; ix += 256) {
    int isup = ix - PAD_T;
    unsigned short vv[7];
    if (isup >= 0 && isup < nsup) {
#pragma unroll
      for (int k = 0; k < 7; ++k)
        vv[k] = f2bf(PSIF[offF + k * nsup + isup] * rc[k]);
    } else {
#pragma unroll
      for (int k = 0; k < 7; ++k) vv[k] = 0;
    }
    if (ix < width) {
#pragma unroll
      for (int k = 0; k < 7; ++k) PSIT[offT + (2 * k) * width + ix] = vv[k];
    }
    if (ix >= 1) {
#pragma unroll
      for (int k = 0; k < 7; ++k) PSIT[offT + (2 * k + 1) * width + ix - 1] = vv[k];
    }
  }
}

// ---------------- kernel 4: persistent pipelined MFMA conv + channel MFMA ---
#define LOADSET(S, CC) {                                                  \
    int v45 = pw16 + (CC);                                                \
    if (v45 < 0) v45 += NC45;                                             \
    if (v45 >= NC45) v45 -= NC45;                                         \
    A##S = *(const short8v*)(XT + (((size_t)tpd * NC45 + v45) << 9) + laneA); \
    int jbIdx = (CC) * 16 + lconst - bLo + PAD_T;                         \
    const unsigned short* bp = pbase + jbIdx + ((jbIdx & 1) ? (wdt - 1) : 0); \
    B##S##0 = *(const short8v*)(bp);                                      \
    B##S##1 = *(const short8v*)(bp + ks);                                 \
    B##S##2 = *(const short8v*)(bp + 2 * ks);                             \
    B##S##3 = *(const short8v*)(bp + 3 * ks);                             \
    B##S##4 = *(const short8v*)(bp + 4 * ks);                             \
    B##S##5 = *(const short8v*)(bp + 5 * ks);                             \
    B##S##6 = *(const short8v*)(bp + 6 * ks); }

#define MFMASET(S) {                                                      \
    acc0 = __builtin_amdgcn_mfma_f32_32x32x16_bf16(A##S, B##S##0, acc0, 0, 0, 0); \
    acc1 = __builtin_amdgcn_mfma_f32_32x32x16_bf16(A##S, B##S##1, acc1, 0, 0, 0); \
    acc2 = __builtin_amdgcn_mfma_f32_32x32x16_bf16(A##S, B##S##2, acc2, 0, 0, 0); \
    acc3 = __builtin_amdgcn_mfma_f32_32x32x16_bf16(A##S, B##S##3, acc3, 0, 0, 0); \
    acc4 = __builtin_amdgcn_mfma_f32_32x32x16_bf16(A##S, B##S##4, acc4, 0, 0, 0); \
    acc5 = __builtin_amdgcn_mfma_f32_32x32x16_bf16(A##S, B##S##5, acc5, 0, 0, 0); \
    acc6 = __builtin_amdgcn_mfma_f32_32x32x16_bf16(A##S, B##S##6, acc6, 0, 0, 0); }

#define DUMPQ(RR) {                                                       \
    int iq = ((RR) & 3) + 8 * ((RR) >> 2) + 4 * g;                        \
    int base = nn * 16 + (iq & 15);                                       \
    b2[0*512+base] = f2bf(acc0[RR]); b2[1*512+base] = f2bf(acc1[RR]);     \
    b2[2*512+base] = f2bf(acc2[RR]); b2[3*512+base] = f2bf(acc3[RR]);     \
    b2[4*512+base] = f2bf(acc4[RR]); b2[5*512+base] = f2bf(acc5[RR]);     \
    b2[6*512+base] = f2bf(acc6[RR]); }

__global__ __launch_bounds__(256, 2) void disco_kernel(
    const unsigned short* __restrict__ XT, const unsigned short* __restrict__ PSIT,
    const unsigned short* __restrict__ w2g, const int* __restrict__ offsT,
    const int* __restrict__ itemPrefix, const int* __restrict__ tband,
    float* __restrict__ y, int* __restrict__ counters) {
  const int tid = threadIdx.x;
  __shared__ __align__(16) unsigned short b2all[4 * 3584];
  __shared__ int Sbuf[362];
  __shared__ int sB[WLAT], sUc[WLAT + 1], sOff[WLAT], sW[WLAT];
  __shared__ int curItem, sLastT;

  // ---- load global item prefix (natural t order) ----
  for (int j = tid; j < 362; j += 256) Sbuf[j] = itemPrefix[j];
  if (tid == 0) sLastT = -1;
  __syncthreads();

  // ---- partition = XCD band (blockIdx%8 ~ round-robin XCD mapping) ----
  const int part8 = blockIdx.x & 7;
  const int tlo = tband[part8], thi = tband[part8 + 1];
  const int iBeg = Sbuf[tlo], iEnd = Sbuf[thi];

  const int lane = tid & 63, wv = tid >> 6, nn = lane & 31, g = lane >> 5;
  const int g8 = g * 8;
  const int laneA = nn * 16 + g8;
  const int lconst = g8 - nn;

  while (true) {
    if (tid == 0) curItem = atomicAdd(&counters[part8], 1);
    __syncthreads();   // also: all waves done with previous item's sB/sUc
    const int m = iBeg + curItem;
    if (m >= iEnd) break;

    int lo = tlo, hi = thi - 1;
    while (lo < hi) {
      int mid = (lo + hi + 1) >> 1;
      if (Sbuf[mid] <= m) lo = mid; else hi = mid - 1;
    }
    const int t = lo;
    const int r = m - Sbuf[t];
    const int pgroup = r % 6;
    const int part = r / 6;

    if (t != sLastT) {   // block-uniform condition
      if (tid < WLAT) {
        int B = windowB(t, tid);
        sB[tid] = B;
        sOff[tid] = offsT[t * 21 + tid];
        sW[tid] = widthOf(B);
      }
      __syncthreads();
      if (tid == 0) {
        int run = 0; sUc[0] = 0;
        for (int d = 0; d < WLAT; ++d) {
          int B = sB[d];
          int np = (B >= 0) ? ((31 + B) >> 4) + ((B + 15) >> 4) + 1 : 0;
          run += np; sUc[d + 1] = run;
        }
        sLastT = t;
      }
    }
    __syncthreads();
    const int Wt = sUc[WLAT];
    int g0 = part * CT, g1 = g0 + CT;
    if (g1 > Wt) g1 = Wt;

    const int ptile = pgroup * 4 + wv;   // 0..23 (23 = dead pad tile)
    const int pw = ptile * 32;
    const int pw16 = ptile * 2;

    f32x16 acc0, acc1, acc2, acc3, acc4, acc5, acc6;
#pragma unroll
    for (int z = 0; z < 16; ++z) {
      acc0[z]=0; acc1[z]=0; acc2[z]=0; acc3[z]=0; acc4[z]=0; acc5[z]=0; acc6[z]=0;
    }

    // ---- hot loop: d-runs with 2-stage software pipeline ----
    short8v A0, A1;
    short8v B00, B01, B02, B03, B04, B05, B06;
    short8v B10, B11, B12, B13, B14, B15, B16;

    int gi = g0;
    int d = 0;
    while (d < WLAT && sUc[d + 1] <= gi) ++d;
    while (gi < g1) {
      const int B = sB[d];
      const int bLo = (B >= 360) ? -360 : -B;
      const int cmin = -((B + 15) >> 4);
      const int tpd = t + d - WOFF;
      const int wdt = sW[d];
      const int ks = 2 * wdt;
      const unsigned short* pbase = PSIT + sOff[d];
      const int rend = sUc[d + 1];
      const int gend = (rend < g1) ? rend : g1;
      const int n = gend - gi;
      int c = cmin + (gi - sUc[d]);

      LOADSET(0, c)
      int it = 0;
      for (; it + 2 <= n; it += 2) {
        LOADSET(1, c + 1)
        MFMASET(0)
        if (it + 2 < n) { LOADSET(0, c + 2) }
        MFMASET(1)
        c += 2;
      }
      if (it < n) { MFMASET(0) }

      gi = gend;
      ++d;
      while (d < WLAT && sUc[d + 1] <= gi) ++d;
    }

    // ---- GEMM2: y[o,p] = sum_{ci=(k,i)} w2[o,ci] * G[ci,p] (wave-private) --
    unsigned short* b2 = b2all + wv * 3584;
    f32x16 Dy;
#pragma unroll
    for (int z = 0; z < 16; ++z) Dy[z] = 0.0f;

    {  // half 0: i in [0,16) <-> regs 0..7
#pragma unroll
      for (int q2 = 0; q2 < 8; ++q2) { DUMPQ(q2) }
#pragma unroll
      for (int k2 = 0; k2 < 7; ++k2) {
        short8v A2 = *(const short8v*)(w2g + (((2 * k2 + 0) * 32 + nn) << 4) + g8);
        short8v B2f = *(const short8v*)(b2 + (k2 << 9) + (nn << 4) + g8);
        Dy = __builtin_amdgcn_mfma_f32_32x32x16_bf16(A2, B2f, Dy, 0, 0, 0);
      }
    }
    {  // half 1: i in [16,32) <-> regs 8..15
#pragma unroll
      for (int q2 = 8; q2 < 16; ++q2) { DUMPQ(q2) }
#pragma unroll
      for (int k2 = 0; k2 < 7; ++k2) {
        short8v A2 = *(const short8v*)(w2g + (((2 * k2 + 1) * 32 + nn) << 4) + g8);
        short8v B2f = *(const short8v*)(b2 + (k2 << 9) + (nn << 4) + g8);
        Dy = __builtin_amdgcn_mfma_f32_32x32x16_bf16(A2, B2f, Dy, 0, 0, 0);
      }
    }

    const int p = pw + nn;
    if (p < NLON_O) {
#pragma unroll
      for (int rr = 0; rr < 16; ++rr) {
        int o = (rr & 3) + 8 * (rr >> 2) + 4 * g;
        atomicAdd(&y[((size_t)o * NLAT_O + t) * NLON_O + p], Dy[rr]);
      }
    }
  }
}

// ---------------- launch ----------------------------------------------------
extern "C" void kernel_launch(void* const* d_in, const int* in_sizes, int n_in,
                              void* d_out, int out_size, void* d_ws, size_t ws_size,
                              hipStream_t stream) {
  (void)in_sizes; (void)n_in; (void)out_size; (void)ws_size;
  const float* x = (const float*)d_in[0];
  const float* w = (const float*)d_in[1];
  float* y = (float*)d_out;

  // ws: XT (16.6MB) | PSIF f32 (24MB cap) | PSIT bf16 (52MB cap) | small tables
  unsigned short* XT = (unsigned short*)d_ws;                 // 8,317,440 shorts
  float* PSIF = (float*)(XT + (size_t)NLAT_O * NC45 * 512);   // cap 6e6 f32
  unsigned short* PSIT = (unsigned short*)(PSIF + 6000000);   // cap 26e6 shorts
  unsigned short* w2 = PSIT + 26000000;                       // 7168
  float* sums = (float*)(w2 + 7168);                          // 2527
  int* offsF = (int*)(sums + NLAT_O * K_N);                   // NE+1
  int* offsT = offsF + NE + 1;                                // NE+1
  int* wtab = offsT + NE + 1;                                 // 361
  int* itemPrefix = wtab + 361;                               // 362
  int* tband = itemPrefix + 362;                              // 9
  int* counters = tband + 9;                                  // 8

  hipMemsetAsync(y, 0, (size_t)CO_N * NLAT_O * NLON_O * sizeof(float), stream);

  prep_kernel<<<1, 256, 0, stream>>>(w, w2, offsF, offsT, wtab, sums,
                                     itemPrefix, tband, counters);
  int n_up = NLAT_O * NC45 * 512;
  upsample_kernel<<<(n_up + 255) / 256, 256, 0, stream>>>(x, XT);
  psi_raw_kernel<<<dim3(NLAT_O, WLAT), 256, 0, stream>>>(offsF, PSIF, sums);
  psi_toep_kernel<<<dim3(NLAT_O, WLAT), 256, 0, stream>>>(offsF, offsT, PSIF, sums, PSIT);
  disco_kernel<<<NBLK, 256, 0, stream>>>(XT, PSIT, w2, offsT, itemPrefix, tband,
                                         y, counters);
}

// Round 10
// 612.265 us; speedup vs baseline: 1.0824x; 1.0824x over previous
//
#include <hip/hip_runtime.h>
#include <hip/hip_bf16.h>
#include <math.h>

#define NLAT_I 240
#define NLON_I 480
#define NLAT_O 361
#define NLON_O 720
#define CI_N 32
#define CO_N 32
#define K_N 7
#define WOFF 10
#define WLAT 21

#define PI_F 3.14159265358979323846f
#define TWOPI_F 6.28318530717958647692f
#define DLAT_V (PI_F / 360.0f)
#define DPHI_V (TWOPI_F / 720.0f)
#define CUTOFF_V (3.25f * PI_F / 120.0f)
#define DR_V (CUTOFF_V / 3.0f)
#define IDR_V (1.0f / DR_V)
#define DPH_V (TWOPI_F / 3.0f)
#define IDPH_V (1.0f / DPH_V)
#define QF_V (DLAT_V * DPHI_V)

#define PAD_T 64        // Toeplitz pad (covers fragment reach beyond support)
#define CT 64           // positions per work item
#define NBLK 512        // 64 blocks per partition x 8 partitions = 2 blocks/CU
#define NC45 45         // 720/16 column chunks
#define NE 7581         // 361*21

typedef __attribute__((ext_vector_type(8))) short short8v;
typedef __attribute__((ext_vector_type(16))) float f32x16;

__device__ __forceinline__ unsigned short f2bf(float f) {
  __hip_bfloat16 h = __float2bfloat16(f);   // RTNE
  union { __hip_bfloat16 b; unsigned short s; } u; u.b = h; return u.s;
}

// ---------------- psi evaluation --------------------------------------------
__device__ __forceinline__ void psi_eval(float ct, float st, float cg, float sg,
                                         float q, float bang, float v[7]) {
  float sb, cb;
  sincosf(bang, &sb, &cb);
  float dx = sg * cb - st;
  float dy = sg * sb;
  float dz = cg - ct;
  float c2 = dx * dx + dy * dy + dz * dz;
  float r = 2.0f * asinf(fminf(1.0f, 0.5f * sqrtf(c2)));
  if (r <= CUTOFF_V) {
    float xx = ct * cb * sg - st * cg;
    float yy = sb * sg;
    float phi = atan2f(yy, xx);
    if (phi < 0.0f) phi += TWOPI_F;
    v[0] = fmaxf(0.0f, 1.0f - r * IDR_V) * q;
#pragma unroll
    for (int k = 1; k < 7; ++k) {
      const float irdr = (float)(1 + (k - 1) / 3) * DR_V;
      const float ipph = (float)((k - 1) % 3) * DPH_V;
      float rad = fmaxf(0.0f, 1.0f - fabsf(r - irdr) * IDR_V);
      float dd = fabsf(phi - ipph);
      dd = fminf(dd, TWOPI_F - dd);
      float az = fmaxf(0.0f, 1.0f - dd * IDPH_V);
      v[k] = rad * az * q;
    }
  } else {
#pragma unroll
    for (int k = 0; k < 7; ++k) v[k] = 0.0f;
  }
}

// per-(t,d) lon window half-width: -1 empty, 360 full circle
__device__ __forceinline__ int windowB(int t, int d) {
  int tp = t + d - WOFF;
  if (tp < 0 || tp > NLAT_O - 1) return -1;
  float th = (float)t * DLAT_V, ga = (float)tp * DLAT_V;
  float st = sinf(th), ct = cosf(th), sg = sinf(ga), cg = cosf(ga);
  float den = st * sg;
  float num = cosf(CUTOFF_V) - ct * cg;
  if (den < 1e-9f) return (fabsf(th - ga) <= CUTOFF_V) ? 360 : -1;
  if (num >= den) return -1;
  if (num <= -den) return 360;
  int B = (int)ceilf(acosf(num / den) * (1.0f / DPHI_V)) + 1;  // +1 margin; psi masks
  return B > 360 ? 360 : B;
}

__device__ __forceinline__ int nsupOf(int B) { return (B >= 360) ? 720 : 2 * B + 1; }
__device__ __forceinline__ int widthOf(int B) {
  return (B < 0) ? 0 : ((nsupOf(B) + 129) & ~1);   // even
}

// ---------------- kernel 0: prep (w2, scans, itemPrefix, counters) ----------
__global__ void prep_kernel(const float* __restrict__ w, unsigned short* __restrict__ w2,
                            int* __restrict__ offsF, int* __restrict__ offsT,
                            int* __restrict__ wtab, float* __restrict__ sums,
                            int* __restrict__ itemPrefix, int* __restrict__ counters) {
  const int tid = threadIdx.x;
  __shared__ int temp[256];
  if (tid < 8) counters[tid * 16] = 0;   // 64B-padded per-partition counters
  for (int idx = tid; idx < 361 * 7; idx += 256) sums[idx] = 0.0f;
  // w2[c16][o][kk] = bf16(w[o][i][k]) with ci=c16*16+kk, k=ci>>5, i=ci&31
  for (int idx = tid; idx < 14 * 32 * 16; idx += 256) {
    int kk = idx & 15; int o = (idx >> 4) & 31; int c16 = idx >> 9;
    int ci = c16 * 16 + kk; int i = ci & 31; int k = ci >> 5;
    w2[idx] = f2bf(w[(o * 32 + i) * 7 + k]);
  }
  for (int e = tid; e < NE; e += 256) {
    int t = e / 21, d = e % 21;
    int B = windowB(t, d);
    offsF[e] = (B >= 0) ? nsupOf(B) * 7 : 0;
    offsT[e] = 14 * widthOf(B);
  }
  for (int t = tid; t < 361; t += 256) {
    int Wt = 0;
    for (int d = 0; d < WLAT; ++d) {
      int B = windowB(t, d);
      if (B >= 0) Wt += ((31 + B) >> 4) + ((B + 15) >> 4) + 1;
    }
    wtab[t] = Wt;
  }
  __syncthreads();
  if (tid == 0) {
    // item prefix in natural t order (bands are cut at item granularity)
    int run = 0;
    for (int t = 0; t < 361; ++t) {
      itemPrefix[t] = run;
      run += 6 * ((wtab[t] + CT - 1) / CT);
    }
    itemPrefix[361] = run;
  }
  __syncthreads();
  // two-level exclusive scan for offsF then offsT (chunk = 30, 256*30 >= NE)
#pragma unroll 1
  for (int pass = 0; pass < 2; ++pass) {
    int* a = pass ? offsT : offsF;
    int s = tid * 30, e = s + 30; if (e > NE) e = NE; if (s > NE) s = NE;
    int sum = 0;
    for (int i = s; i < e; ++i) sum += a[i];
    temp[tid] = sum;
    __syncthreads();
    if (tid == 0) {
      int run = 0;
      for (int i = 0; i < 256; ++i) { int v = temp[i]; temp[i] = run; run += v; }
      a[NE] = run;
    }
    __syncthreads();
    int run = temp[tid];
    for (int i = s; i < e; ++i) { int v = a[i]; a[i] = run; run += v; }
    __syncthreads();
  }
}

// ---------------- kernel 1: bilinear upsample -> tiled bf16 XT --------------
// XT[t][c][i][kk] with b = c*16+kk  (wave A-load = contiguous 1KB)
__global__ void upsample_kernel(const float* __restrict__ x,
                                unsigned short* __restrict__ XT) {
  int idx = blockIdx.x * 256 + threadIdx.x;
  if (idx >= NLAT_O * NC45 * 512) return;
  int kk = idx & 15;
  int i = (idx >> 4) & 31;
  int c = (idx >> 9) % NC45;
  int t = idx / (NC45 * 512);
  int p = c * 16 + kk;

  double post = (double)t * (239.0 / 360.0);
  int i0 = (int)floor(post);
  if (i0 < 0) i0 = 0;
  if (i0 > NLAT_I - 1) i0 = NLAT_I - 1;
  int i1 = i0 + 1; if (i1 > NLAT_I - 1) i1 = NLAT_I - 1;
  float wt = (float)(post - (double)i0);

  double posp = (double)p * (2.0 / 3.0);
  double j0f = floor(posp);
  int j0 = ((int)j0f) % NLON_I;
  int j1 = (j0 + 1) % NLON_I;
  float wp = (float)(posp - j0f);

  const float* xi = x + (size_t)i * (NLAT_I * NLON_I);
  float a = xi[i0 * NLON_I + j0];
  float b = xi[i0 * NLON_I + j1];
  float cc = xi[i1 * NLON_I + j0];
  float d = xi[i1 * NLON_I + j1];
  float l0 = (1.0f - wt) * a + wt * cc;
  float l1 = (1.0f - wt) * b + wt * d;
  XT[idx] = f2bf((1.0f - wp) * l0 + wp * l1);
}

// ---------------- kernel 2: raw psi (f32) + fused per-(k,t) partial sums ----
__global__ void psi_raw_kernel(const int* __restrict__ offsF,
                               float* __restrict__ PSIF,
                               float* __restrict__ sums) {
  int t = blockIdx.x, d = blockIdx.y;
  int B = windowB(t, d);
  if (B < 0) return;
  int nsup = nsupOf(B);
  int bLo = (B >= 360) ? -360 : -B;
  int offF = offsF[t * 21 + d];
  int tp = t + d - WOFF;
  float th = (float)t * DLAT_V, ga = (float)tp * DLAT_V;
  float st, ct, sg, cg;
  sincosf(th, &st, &ct);
  sincosf(ga, &sg, &cg);
  float q = sg * QF_V;
  float acc[7];
#pragma unroll
  for (int k = 0; k < 7; ++k) acc[k] = 0.0f;
  for (int ix = threadIdx.x; ix < nsup; ix += 256) {
    float v[7];
    psi_eval(ct, st, cg, sg, q, (float)(bLo + ix) * DPHI_V, v);
#pragma unroll
    for (int k = 0; k < 7; ++k) { PSIF[offF + k * nsup + ix] = v[k]; acc[k] += v[k]; }
  }
#pragma unroll
  for (int k = 0; k < 7; ++k) {
    float a = acc[k];
    for (int off = 32; off > 0; off >>= 1) a += __shfl_down(a, off, 64);
    acc[k] = a;
  }
  __shared__ float red[4][7];
  int wid = threadIdx.x >> 6;
  if ((threadIdx.x & 63) == 0) {
#pragma unroll
    for (int k = 0; k < 7; ++k) red[wid][k] = acc[k];
  }
  __syncthreads();
  if (threadIdx.x == 0) {
#pragma unroll
    for (int k = 0; k < 7; ++k)
      atomicAdd(&sums[t * 7 + k], red[0][k] + red[1][k] + red[2][k] + red[3][k]);
  }
}

// ---------------- kernel 3: normalized bf16 Toeplitz (2 parity copies) ------
__global__ void psi_toep_kernel(const int* __restrict__ offsF,
                                const int* __restrict__ offsT,
                                const float* __restrict__ PSIF,
                                const float* __restrict__ sums,
                                unsigned short* __restrict__ PSIT) {
  int t = blockIdx.x, d = blockIdx.y;
  int B = windowB(t, d);
  if (B < 0) return;
  int nsup = nsupOf(B);
  int width = widthOf(B);
  int offF = offsF[t * 21 + d];
  int offT = offsT[t * 21 + d];
  float rc[7];
#pragma unroll
  for (int k = 0; k < 7; ++k) rc[k] = 1.0f / fmaxf(sums[t * 7 + k], 1e-8f);
  for (int ix = threadIdx.x; ix <= width; ix += 256) {
    int isup = ix - PAD_T;
    unsigned short vv[7];
    if (isup >= 0 && isup < nsup) {
#pragma unroll
      for (int k = 0; k < 7; ++k)
        vv[k] = f2bf(PSIF[offF + k * nsup + isup] * rc[k]);
    } else {
#pragma unroll
      for (int k = 0; k < 7; ++k) vv[k] = 0;
    }
    if (ix < width) {
#pragma unroll
      for (int k = 0; k < 7; ++k) PSIT[offT + (2 * k) * width + ix] = vv[k];
    }
    if (ix >= 1) {
#pragma unroll
      for (int k = 0; k < 7; ++k) PSIT[offT + (2 * k + 1) * width + ix - 1] = vv[k];
    }
  }
}

// ---------------- kernel 4: persistent pipelined MFMA conv + channel MFMA ---
#define LOADSET(S, CC) {                                                  \
    int v45 = pw16 + (CC);                                                \
    if (v45 < 0) v45 += NC45;                                             \
    if (v45 >= NC45) v45 -= NC45;                                         \
    A##S = *(const short8v*)(XT + (((size_t)tpd * NC45 + v45) << 9) + laneA); \
    int jbIdx = (CC) * 16 + lconst - bLo + PAD_T;                         \
    const unsigned short* bp = pbase + jbIdx + ((jbIdx & 1) ? (wdt - 1) : 0); \
    B##S##0 = *(const short8v*)(bp);                                      \
    B##S##1 = *(const short8v*)(bp + ks);                                 \
    B##S##2 = *(const short8v*)(bp + 2 * ks);                             \
    B##S##3 = *(const short8v*)(bp + 3 * ks);                             \
    B##S##4 = *(const short8v*)(bp + 4 * ks);                             \
    B##S##5 = *(const short8v*)(bp + 5 * ks);                             \
    B##S##6 = *(const short8v*)(bp + 6 * ks); }

#define MFMASET(S) {                                                      \
    acc0 = __builtin_amdgcn_mfma_f32_32x32x16_bf16(A##S, B##S##0, acc0, 0, 0, 0); \
    acc1 = __builtin_amdgcn_mfma_f32_32x32x16_bf16(A##S, B##S##1, acc1, 0, 0, 0); \
    acc2 = __builtin_amdgcn_mfma_f32_32x32x16_bf16(A##S, B##S##2, acc2, 0, 0, 0); \
    acc3 = __builtin_amdgcn_mfma_f32_32x32x16_bf16(A##S, B##S##3, acc3, 0, 0, 0); \
    acc4 = __builtin_amdgcn_mfma_f32_32x32x16_bf16(A##S, B##S##4, acc4, 0, 0, 0); \
    acc5 = __builtin_amdgcn_mfma_f32_32x32x16_bf16(A##S, B##S##5, acc5, 0, 0, 0); \
    acc6 = __builtin_amdgcn_mfma_f32_32x32x16_bf16(A##S, B##S##6, acc6, 0, 0, 0); }

#define DUMPQ(RR) {                                                       \
    int iq = ((RR) & 3) + 8 * ((RR) >> 2) + 4 * g;                        \
    int base = nn * 16 + (iq & 15);                                       \
    b2[0*512+base] = f2bf(acc0[RR]); b2[1*512+base] = f2bf(acc1[RR]);     \
    b2[2*512+base] = f2bf(acc2[RR]); b2[3*512+base] = f2bf(acc3[RR]);     \
    b2[4*512+base] = f2bf(acc4[RR]); b2[5*512+base] = f2bf(acc5[RR]);     \
    b2[6*512+base] = f2bf(acc6[RR]); }

__global__ __launch_bounds__(256, 2) void disco_kernel(
    const unsigned short* __restrict__ XT, const unsigned short* __restrict__ PSIT,
    const unsigned short* __restrict__ w2g, const int* __restrict__ offsT,
    const int* __restrict__ itemPrefix, float* __restrict__ y,
    int* __restrict__ counters) {
  const int tid = threadIdx.x;
  __shared__ __align__(16) unsigned short b2all[4 * 3584];
  __shared__ int Sbuf[362];
  __shared__ int sB[WLAT], sUc[WLAT + 1], sOff[WLAT], sW[WLAT];
  __shared__ int curItem, sLastT;

  // ---- load global item prefix (natural t order) ----
  for (int j = tid; j < 362; j += 256) Sbuf[j] = itemPrefix[j];
  if (tid == 0) sLastT = -1;
  __syncthreads();

  // ---- partition = XCD band, cut at ITEM granularity (near-exact balance) --
  const int part8 = blockIdx.x & 7;
  const int NTOT = Sbuf[361];
  const int iBeg = (int)(((long)NTOT * part8) >> 3);
  const int iEnd = (int)(((long)NTOT * (part8 + 1)) >> 3);

  const int lane = tid & 63, wv = tid >> 6, nn = lane & 31, g = lane >> 5;
  const int g8 = g * 8;
  const int laneA = nn * 16 + g8;
  const int lconst = g8 - nn;

  while (true) {
    if (tid == 0) curItem = atomicAdd(&counters[part8 * 16], 1);
    __syncthreads();   // also: all waves done with previous item's sB/sUc
    const int m = iBeg + curItem;
    if (m >= iEnd) break;

    int lo = 0, hi = 360;
    while (lo < hi) {
      int mid = (lo + hi + 1) >> 1;
      if (Sbuf[mid] <= m) lo = mid; else hi = mid - 1;
    }
    const int t = lo;
    const int r = m - Sbuf[t];
    const int pgroup = r % 6;
    const int part = r / 6;

    if (t != sLastT) {   // block-uniform condition
      if (tid < WLAT) {
        int B = windowB(t, tid);
        sB[tid] = B;
        sOff[tid] = offsT[t * 21 + tid];
        sW[tid] = widthOf(B);
      }
      __syncthreads();
      if (tid == 0) {
        int run = 0; sUc[0] = 0;
        for (int d = 0; d < WLAT; ++d) {
          int B = sB[d];
          int np = (B >= 0) ? ((31 + B) >> 4) + ((B + 15) >> 4) + 1 : 0;
          run += np; sUc[d + 1] = run;
        }
        sLastT = t;
      }
    }
    __syncthreads();
    const int Wt = sUc[WLAT];
    int g0 = part * CT, g1 = g0 + CT;
    if (g1 > Wt) g1 = Wt;

    const int ptile = pgroup * 4 + wv;   // 0..23 (23 = dead pad tile)
    const int pw = ptile * 32;
    const int pw16 = ptile * 2;

    f32x16 acc0, acc1, acc2, acc3, acc4, acc5, acc6;
#pragma unroll
    for (int z = 0; z < 16; ++z) {
      acc0[z]=0; acc1[z]=0; acc2[z]=0; acc3[z]=0; acc4[z]=0; acc5[z]=0; acc6[z]=0;
    }

    // ---- hot loop: d-runs with 2-stage software pipeline ----
    short8v A0, A1;
    short8v B00, B01, B02, B03, B04, B05, B06;
    short8v B10, B11, B12, B13, B14, B15, B16;

    int gi = g0;
    int d = 0;
    while (d < WLAT && sUc[d + 1] <= gi) ++d;
    while (gi < g1) {
      const int B = sB[d];
      const int bLo = (B >= 360) ? -360 : -B;
      const int cmin = -((B + 15) >> 4);
      const int tpd = t + d - WOFF;
      const int wdt = sW[d];
      const int ks = 2 * wdt;
      const unsigned short* pbase = PSIT + sOff[d];
      const int rend = sUc[d + 1];
      const int gend = (rend < g1) ? rend : g1;
      const int n = gend - gi;
      int c = cmin + (gi - sUc[d]);

      LOADSET(0, c)
      int it = 0;
      for (; it + 2 <= n; it += 2) {
        LOADSET(1, c + 1)
        MFMASET(0)
        if (it + 2 < n) { LOADSET(0, c + 2) }
        MFMASET(1)
        c += 2;
      }
      if (it < n) { MFMASET(0) }

      gi = gend;
      ++d;
      while (d < WLAT && sUc[d + 1] <= gi) ++d;
    }

    // ---- GEMM2: y[o,p] = sum_{ci=(k,i)} w2[o,ci] * G[ci,p] (wave-private) --
    unsigned short* b2 = b2all + wv * 3584;
    f32x16 Dy;
#pragma unroll
    for (int z = 0; z < 16; ++z) Dy[z] = 0.0f;

    {  // half 0: i in [0,16) <-> regs 0..7
#pragma unroll
      for (int q2 = 0; q2 < 8; ++q2) { DUMPQ(q2) }
#pragma unroll
      for (int k2 = 0; k2 < 7; ++k2) {
        short8v A2 = *(const short8v*)(w2g + (((2 * k2 + 0) * 32 + nn) << 4) + g8);
        short8v B2f = *(const short8v*)(b2 + (k2 << 9) + (nn << 4) + g8);
        Dy = __builtin_amdgcn_mfma_f32_32x32x16_bf16(A2, B2f, Dy, 0, 0, 0);
      }
    }
    {  // half 1: i in [16,32) <-> regs 8..15
#pragma unroll
      for (int q2 = 8; q2 < 16; ++q2) { DUMPQ(q2) }
#pragma unroll
      for (int k2 = 0; k2 < 7; ++k2) {
        short8v A2 = *(const short8v*)(w2g + (((2 * k2 + 1) * 32 + nn) << 4) + g8);
        short8v B2f = *(const short8v*)(b2 + (k2 << 9) + (nn << 4) + g8);
        Dy = __builtin_amdgcn_mfma_f32_32x32x16_bf16(A2, B2f, Dy, 0, 0, 0);
      }
    }

    const int p = pw + nn;
    if (p < NLON_O) {
#pragma unroll
      for (int rr = 0; rr < 16; ++rr) {
        int o = (rr & 3) + 8 * (rr >> 2) + 4 * g;
        atomicAdd(&y[((size_t)o * NLAT_O + t) * NLON_O + p], Dy[rr]);
      }
    }
  }
}

// ---------------- launch ----------------------------------------------------
extern "C" void kernel_launch(void* const* d_in, const int* in_sizes, int n_in,
                              void* d_out, int out_size, void* d_ws, size_t ws_size,
                              hipStream_t stream) {
  (void)in_sizes; (void)n_in; (void)out_size; (void)ws_size;
  const float* x = (const float*)d_in[0];
  const float* w = (const float*)d_in[1];
  float* y = (float*)d_out;

  // ws: XT (16.6MB) | PSIF f32 (24MB cap) | PSIT bf16 (52MB cap) | small tables
  unsigned short* XT = (unsigned short*)d_ws;                 // 8,317,440 shorts
  float* PSIF = (float*)(XT + (size_t)NLAT_O * NC45 * 512);   // cap 6e6 f32
  unsigned short* PSIT = (unsigned short*)(PSIF + 6000000);   // cap 26e6 shorts
  unsigned short* w2 = PSIT + 26000000;                       // 7168
  float* sums = (float*)(w2 + 7168);                          // 2527
  int* offsF = (int*)(sums + NLAT_O * K_N);                   // NE+1
  int* offsT = offsF + NE + 1;                                // NE+1
  int* wtab = offsT + NE + 1;                                 // 361
  int* itemPrefix = wtab + 361;                               // 362
  int* counters = itemPrefix + 362;                           // 8*16 (64B pad)

  hipMemsetAsync(y, 0, (size_t)CO_N * NLAT_O * NLON_O * sizeof(float), stream);

  prep_kernel<<<1, 256, 0, stream>>>(w, w2, offsF, offsT, wtab, sums,
                                     itemPrefix, counters);
  int n_up = NLAT_O * NC45 * 512;
  upsample_kernel<<<(n_up + 255) / 256, 256, 0, stream>>>(x, XT);
  psi_raw_kernel<<<dim3(NLAT_O, WLAT), 256, 0, stream>>>(offsF, PSIF, sums);
  psi_toep_kernel<<<dim3(NLAT_O, WLAT), 256, 0, stream>>>(offsF, offsT, PSIF, sums, PSIT);
  disco_kernel<<<NBLK, 256, 0, stream>>>(XT, PSIT, w2, offsT, itemPrefix,
                                         y, counters);
}